// Round 12
// baseline (389.024 us; speedup 1.0000x reference)
//
#include <hip/hip_runtime.h>
#include <math.h>
#include <stdint.h>

typedef _Float16 half8v __attribute__((ext_vector_type(8)));
typedef _Float16 half4v __attribute__((ext_vector_type(4)));
typedef _Float16 half2v __attribute__((ext_vector_type(2)));
typedef __fp16 fp16x2 __attribute__((ext_vector_type(2)));
typedef float floatx4 __attribute__((ext_vector_type(4)));

#define MFMA16(a, b, c) __builtin_amdgcn_mfma_f32_16x16x32_f16(a, b, c, 0, 0, 0)

// Q pre-scale: 1/sqrt(64) * log2(e), folded so attention uses exp2 directly.
#define QSCALE 0.18033688011112f

// Async global->LDS, 16B per lane. LDS dest must be wave-uniform base + lane*16;
// the GLOBAL source address is per-lane arbitrary (it's a gather).
__device__ __forceinline__ void gld_lds16(const void* g, void* l) {
  __builtin_amdgcn_global_load_lds(
      (const __attribute__((address_space(1))) uint32_t*)(uintptr_t)g,
      (__attribute__((address_space(3))) uint32_t*)(uintptr_t)l, 16, 0, 0);
}

// Packed f32x2 -> f16x2 (rtz), bit-cast to our _Float16 vector type.
__device__ __forceinline__ half2v pk16(float a, float b) {
  fp16x2 t = __builtin_amdgcn_cvt_pkrtz(a, b);
  return __builtin_bit_cast(half2v, t);
}

// LDS bank swizzle for 64-col fp16 tiles, 16B blocks.
__device__ __forceinline__ int swz(int row, int blk) {
  return row * 64 + ((blk ^ (row & 7)) << 3);
}

// ---------------------------------------------------------------------------
// Software grid barrier (normal launch; co-residency GUARANTEED by
// construction: 512 blocks, 48 KB LDS + launch_bounds(256,2) VGPR cap 256
// -> >= 2 blocks/CU always -> all 512 resident on 256 CUs).
// Monotonic counter, zeroed per launch by hipMemsetAsync. Agent-scope
// release on the add publishes this block's writes (L2 writeback); agent-
// scope acquire on the spin load invalidates stale L1/L2 lines (G16).
// ---------------------------------------------------------------------------
__device__ int g_bar;

__device__ __forceinline__ void grid_barrier(int target) {
  __syncthreads();
  if (threadIdx.x == 0) {
    __hip_atomic_fetch_add(&g_bar, 1, __ATOMIC_ACQ_REL,
                           __HIP_MEMORY_SCOPE_AGENT);
    while (__hip_atomic_load(&g_bar, __ATOMIC_ACQUIRE,
                             __HIP_MEMORY_SCOPE_AGENT) < target)
      __builtin_amdgcn_s_sleep(16);
  }
  __syncthreads();
}

// ---------------------------------------------------------------------------
// ONE kernel, 4 phases separated by grid_barrier():
//   0: X fp32->fp16 + weight transpose (3072 jobs, 6/block)
//   1: QKV projection (768 jobs, strided)
//   2: flash attention (512 jobs, 1:1; Q-tile 128, 4 waves; XCD-local heads)
//   3: out projection (512 jobs, 1:1)
// Removes 3 kernel-launch boundaries (~20 us each, from the R2..R10 budget
// fit: modeled bodies + N*20us matches every measured total).
// ---------------------------------------------------------------------------
__global__ __launch_bounds__(256, 2) void mega(
    const float* __restrict__ X, const float* __restrict__ Wq,
    const float* __restrict__ Wkv, const float* __restrict__ Wo,
    const float* __restrict__ bo,
    _Float16* __restrict__ X16, _Float16* __restrict__ WqkvT,
    _Float16* __restrict__ WoT,
    _Float16* __restrict__ q_ws, _Float16* __restrict__ k_ws,
    _Float16* __restrict__ vT_ws,
    _Float16* __restrict__ aout, float* __restrict__ Out)
{
  __shared__ alignas(16) _Float16 pool[24576];  // 48 KB, re-carved per phase
  const int bid = blockIdx.x;
  const int tid = threadIdx.x;
  const int wave = tid >> 6, lane = tid & 63;
  const int qd = lane >> 4, l15 = lane & 15;

  // ===== Phase 0: prep ====================================================
  for (int j = bid; j < 3072; j += 512) {
    if (j < 2048) {
      size_t gid = (size_t)j * 256 + tid;
      const float4* src = (const float4*)X + gid * 2;
      float4 a = src[0], b = src[1];
      half8v h;
      h[0]=(_Float16)a.x; h[1]=(_Float16)a.y; h[2]=(_Float16)a.z; h[3]=(_Float16)a.w;
      h[4]=(_Float16)b.x; h[5]=(_Float16)b.y; h[6]=(_Float16)b.z; h[7]=(_Float16)b.w;
      *((half8v*)X16 + gid) = h;
    } else {
      int b = j - 2048;
      const float* src; _Float16* dst; int N, tk, tn;
      if (b < 256)      { src = Wq;  dst = WqkvT;                       N = 1024; tk = b & 15;        tn = b >> 4; }
      else if (b < 768) { src = Wkv; dst = WqkvT + (size_t)1024 * 1024; N = 2048; tk = (b - 256) & 15; tn = (b - 256) >> 4; }
      else              { src = Wo;  dst = WoT;                         N = 1024; tk = (b - 768) & 15; tn = (b - 768) >> 4; }
      __syncthreads();  // pool reuse guard between tile jobs
      {
        int kg = tid >> 4, ng = tid & 15;
        const float* sp = src + (size_t)(tk * 64 + kg * 4) * N + tn * 64 + ng * 4;
        float4 r0 = *(const float4*)(sp);
        float4 r1 = *(const float4*)(sp + N);
        float4 r2 = *(const float4*)(sp + 2 * N);
        float4 r3 = *(const float4*)(sp + 3 * N);
        half4v h;
        h[0]=(_Float16)r0.x; h[1]=(_Float16)r1.x; h[2]=(_Float16)r2.x; h[3]=(_Float16)r3.x;
        *(half4v*)&pool[(ng * 4 + 0) * 68 + kg * 4] = h;
        h[0]=(_Float16)r0.y; h[1]=(_Float16)r1.y; h[2]=(_Float16)r2.y; h[3]=(_Float16)r3.y;
        *(half4v*)&pool[(ng * 4 + 1) * 68 + kg * 4] = h;
        h[0]=(_Float16)r0.z; h[1]=(_Float16)r1.z; h[2]=(_Float16)r2.z; h[3]=(_Float16)r3.z;
        *(half4v*)&pool[(ng * 4 + 2) * 68 + kg * 4] = h;
        h[0]=(_Float16)r0.w; h[1]=(_Float16)r1.w; h[2]=(_Float16)r2.w; h[3]=(_Float16)r3.w;
        *(half4v*)&pool[(ng * 4 + 3) * 68 + kg * 4] = h;
      }
      __syncthreads();
      #pragma unroll
      for (int i = 0; i < 2; i++) {
        int idx = tid + i * 256;
        int nl = idx >> 3, k8 = (idx & 7) * 8;
        half8v v = *(half8v*)&pool[nl * 68 + k8];
        *(half8v*)(dst + (size_t)(tn * 64 + nl) * 1024 + tk * 64 + k8) = v;
      }
    }
  }
  grid_barrier(512);

  // ===== Phase 1: QKV projection (768 jobs, strided) ======================
  for (int jj = bid; jj < 768; jj += 512) {
    __syncthreads();  // pool reuse guard between jobs
    constexpr int K = 1024;
    _Float16* As = pool;          // 128x32
    _Float16* Bs = pool + 4096;   // 128x32
    const int m0 = (jj & 31) * 128;
    const int n0 = (jj >> 5) * 128;  // 0..23
    const int wr = (wave >> 1) * 64, wc = (wave & 1) * 64;
    const int r0i = tid >> 2, c0 = (tid & 3) * 8;

    floatx4 acc[4][4] = {};
    for (int k0 = 0; k0 < K; k0 += 32) {
      gld_lds16(X16 + (size_t)(m0 + r0i) * K + k0 + c0, &As[tid * 8]);
      gld_lds16(X16 + (size_t)(m0 + 64 + r0i) * K + k0 + c0, &As[(tid + 256) * 8]);
      gld_lds16(WqkvT + (size_t)(n0 + r0i) * K + k0 + c0, &Bs[tid * 8]);
      gld_lds16(WqkvT + (size_t)(n0 + 64 + r0i) * K + k0 + c0, &Bs[(tid + 256) * 8]);
      __syncthreads();
      half8v a[4], b[4];
      #pragma unroll
      for (int it = 0; it < 4; it++)
        a[it] = *(half8v*)&As[(wr + it * 16 + l15) * 32 + qd * 8];
      #pragma unroll
      for (int jt = 0; jt < 4; jt++)
        b[jt] = *(half8v*)&Bs[(wc + jt * 16 + l15) * 32 + qd * 8];
      #pragma unroll
      for (int it = 0; it < 4; it++)
        #pragma unroll
        for (int jt = 0; jt < 4; jt++)
          acc[it][jt] = MFMA16(a[it], b[jt], acc[it][jt]);
      __syncthreads();
    }

    if (n0 < 2048) {
      #pragma unroll
      for (int it = 0; it < 4; it++) {
        #pragma unroll
        for (int jt = 0; jt < 4; jt++) {
          #pragma unroll
          for (int r = 0; r < 4; r++) {
            int m = m0 + wr + it * 16 + qd * 4 + r;
            int n = n0 + wc + jt * 16 + l15;
            float val = acc[it][jt][r];
            int bb = m >> 11, nn = m & 2047;
            if (n0 < 1024) {
              int h = n >> 6, d = n & 63;
              q_ws[(((size_t)bb * 16 + h) * 2048 + nn) * 64 + d] = (_Float16)(val * QSCALE);
            } else {
              int c = n - 1024, h = c >> 6, d = c & 63;
              k_ws[(((size_t)bb * 16 + h) * 2048 + nn) * 64 + d] = (_Float16)val;
            }
          }
        }
      }
    } else {
      // vT epilogue: transpose via pool (128x136 = 17408 halves <= 24576).
      #pragma unroll
      for (int it = 0; it < 4; it++) {
        #pragma unroll
        for (int jt = 0; jt < 4; jt++) {
          #pragma unroll
          for (int r = 0; r < 4; r++) {
            int ml = wr + it * 16 + qd * 4 + r;
            int nl = wc + jt * 16 + l15;
            pool[nl * 136 + ml] = (_Float16)acc[it][jt][r];
          }
        }
      }
      __syncthreads();
      int row = tid >> 1;
      int mh  = (tid & 1) * 64;
      int c   = (n0 - 2048) + row;
      int bb  = m0 >> 11;
      int nnb = (m0 & 2047) + mh;
      _Float16* dstp =
          vT_ws + (((size_t)bb * 16 + (c >> 6)) * 64 + (c & 63)) * 2048 + nnb;
      #pragma unroll
      for (int i = 0; i < 8; i++)
        *(half8v*)(dstp + i * 8) = *(half8v*)&pool[row * 136 + mh + i * 8];
    }
  }
  grid_barrier(1024);

  // ===== Phase 2: flash attention (512 jobs, 1:1) =========================
  {
    constexpr int N = 2048;
    _Float16* Qs  = pool;           // 128x64 (Q -> P buffer)
    _Float16* Ks  = pool + 8192;    // 2 x 4096 (double-buffered K)
    _Float16* Vts = pool + 16384;   // 2 x 4096 (double-buffered V^T)

    // bid&7 ~ XCD: 4 whole heads per XCD for K/V L2 residency.
    const int bh = ((bid >> 7) << 3) | (bid & 7);
    const int qt = (bid >> 3) & 15;
    const int q0 = qt * 128;
    const int wbase = wave * 32;  // 4 waves x 32 q-rows = Q-tile 128

    const _Float16* Qp = q_ws + (size_t)bh * N * 64;
    const _Float16* Kp = k_ws + (size_t)bh * N * 64;
    const _Float16* Vp = vT_ws + (size_t)bh * 64 * N;

    #pragma unroll
    for (int i = 0; i < 4; i++) {
      int idx = tid + i * 256;
      int r = idx >> 3, cb = (idx ^ r) & 7;
      gld_lds16(Qp + (size_t)(q0 + r) * 64 + cb * 8, &Qs[idx * 8]);
    }
    #pragma unroll
    for (int i = 0; i < 2; i++) {
      int idx = tid + i * 256;
      int r = idx >> 3, cb = (idx ^ r) & 7;
      gld_lds16(Kp + (size_t)r * 64 + cb * 8, &Ks[idx * 8]);
      gld_lds16(Vp + (size_t)r * N + cb * 8, &Vts[idx * 8]);
    }
    __syncthreads();

    half8v qf[2][2];
    #pragma unroll
    for (int m = 0; m < 2; m++)
      #pragma unroll
      for (int ks = 0; ks < 2; ks++)
        qf[m][ks] = *(half8v*)&Qs[swz(wbase + m * 16 + l15, ks * 4 + qd)];

    floatx4 o[2][4] = {};
    float lsum[2] = {};

    int p = 0;
    for (int kv0 = 0; kv0 < N; kv0 += 64) {
      const bool more = (kv0 + 64) < N;
      if (more) {
        int kvn = kv0 + 64;
        #pragma unroll
        for (int i = 0; i < 2; i++) {
          int idx = tid + i * 256;
          int r = idx >> 3, cb = (idx ^ r) & 7;
          gld_lds16(Kp + (size_t)(kvn + r) * 64 + cb * 8,
                    &Ks[(p ^ 1) * 4096 + idx * 8]);
          gld_lds16(Vp + (size_t)r * N + kvn + cb * 8,
                    &Vts[(p ^ 1) * 4096 + idx * 8]);
        }
      }

      // S^T = K·Q^T : s[nt][m] C-layout kv = nt*16+qd*4+r, q = m*16+l15.
      floatx4 s[4][2] = {};
      #pragma unroll
      for (int ks = 0; ks < 2; ks++) {
        half8v kf[4];
        #pragma unroll
        for (int nt = 0; nt < 4; nt++)
          kf[nt] = *(half8v*)&Ks[p * 4096 + swz(nt * 16 + l15, ks * 4 + qd)];
        #pragma unroll
        for (int nt = 0; nt < 4; nt++)
          #pragma unroll
          for (int m = 0; m < 2; m++)
            s[nt][m] = MFMA16(kf[nt], qf[m][ks], s[nt][m]);
      }

      // p = 2^s; partial row sums; pack half4 -> wave-private P rows of Qs.
      #pragma unroll
      for (int m = 0; m < 2; m++) {
        #pragma unroll
        for (int nt = 0; nt < 4; nt++) {
          float p0 = __builtin_amdgcn_exp2f(s[nt][m][0]);
          float p1 = __builtin_amdgcn_exp2f(s[nt][m][1]);
          float p2 = __builtin_amdgcn_exp2f(s[nt][m][2]);
          float p3 = __builtin_amdgcn_exp2f(s[nt][m][3]);
          lsum[m] += (p0 + p1) + (p2 + p3);
          half2v h01 = pk16(p0, p1);
          half2v h23 = pk16(p2, p3);
          half4v pk;
          pk[0] = h01[0]; pk[1] = h01[1]; pk[2] = h23[0]; pk[3] = h23[1];
          *(half4v*)&Qs[swz(wbase + m * 16 + l15, 2 * nt + (qd >> 1)) +
                        (qd & 1) * 4] = pk;
        }
      }

      // O += P·V, full-rate K=32 MFMA.
      #pragma unroll
      for (int ks = 0; ks < 2; ks++) {
        half8v pf[2], vf[4];
        #pragma unroll
        for (int m = 0; m < 2; m++)
          pf[m] = *(half8v*)&Qs[swz(wbase + m * 16 + l15, 4 * ks + qd)];
        #pragma unroll
        for (int nt = 0; nt < 4; nt++)
          vf[nt] = *(half8v*)&Vts[p * 4096 + swz(nt * 16 + l15, 4 * ks + qd)];
        #pragma unroll
        for (int m = 0; m < 2; m++)
          #pragma unroll
          for (int nt = 0; nt < 4; nt++)
            o[m][nt] = MFMA16(pf[m], vf[nt], o[m][nt]);
      }

      if (more) __syncthreads();
      p ^= 1;
    }

    #pragma unroll
    for (int m = 0; m < 2; m++) {
      lsum[m] += __shfl_xor(lsum[m], 16);
      lsum[m] += __shfl_xor(lsum[m], 32);
    }

    const int bb = bh >> 4, hh = bh & 15;
    #pragma unroll
    for (int m = 0; m < 2; m++) {
      #pragma unroll
      for (int r = 0; r < 4; r++) {
        float inv = 1.0f / __shfl(lsum[m], qd * 4 + r);
        int n = q0 + wbase + m * 16 + qd * 4 + r;
        #pragma unroll
        for (int dt = 0; dt < 4; dt++) {
          int d = dt * 16 + l15;
          aout[((size_t)(bb * 2048 + n)) * 1024 + hh * 64 + d] =
              (_Float16)(o[m][dt][r] * inv);
        }
      }
    }
  }
  grid_barrier(1536);

  // ===== Phase 3: out projection (512 jobs, 1:1) ==========================
  {
    constexpr int K = 1024;
    _Float16* As = pool;          // 64x32
    _Float16* Bs = pool + 2048;   // 128x32
    const int m0 = (bid & 63) * 64;
    const int n0 = (bid >> 6) * 128;
    const int wr = (wave >> 1) * 32, wc = (wave & 1) * 64;
    const int r0i = tid >> 2, c0 = (tid & 3) * 8;

    floatx4 acc[2][4] = {};
    for (int k0 = 0; k0 < K; k0 += 32) {
      gld_lds16(aout + (size_t)(m0 + r0i) * K + k0 + c0, &As[tid * 8]);
      gld_lds16(WoT + (size_t)(n0 + r0i) * K + k0 + c0, &Bs[tid * 8]);
      gld_lds16(WoT + (size_t)(n0 + 64 + r0i) * K + k0 + c0, &Bs[(tid + 256) * 8]);
      __syncthreads();
      half8v a[2], b[4];
      #pragma unroll
      for (int it = 0; it < 2; it++)
        a[it] = *(half8v*)&As[(wr + it * 16 + l15) * 32 + qd * 8];
      #pragma unroll
      for (int jt = 0; jt < 4; jt++)
        b[jt] = *(half8v*)&Bs[(wc + jt * 16 + l15) * 32 + qd * 8];
      #pragma unroll
      for (int it = 0; it < 2; it++)
        #pragma unroll
        for (int jt = 0; jt < 4; jt++)
          acc[it][jt] = MFMA16(a[it], b[jt], acc[it][jt]);
      __syncthreads();
    }

    #pragma unroll
    for (int it = 0; it < 2; it++) {
      #pragma unroll
      for (int jt = 0; jt < 4; jt++) {
        int n = n0 + wc + jt * 16 + l15;
        float bias = bo[n];
        #pragma unroll
        for (int r = 0; r < 4; r++) {
          int m = m0 + wr + it * 16 + qd * 4 + r;
          Out[(size_t)m * 1024 + n] = acc[it][jt][r] + bias;
        }
      }
    }
  }
}

// ---------------------------------------------------------------------------
extern "C" void kernel_launch(void* const* d_in, const int* in_sizes, int n_in,
                              void* d_out, int out_size, void* d_ws, size_t ws_size,
                              hipStream_t stream) {
  const float* X   = (const float*)d_in[0];
  const float* Wq  = (const float*)d_in[1];
  const float* Wkv = (const float*)d_in[2];
  const float* Wo  = (const float*)d_in[3];
  const float* bo  = (const float*)d_in[4];
  float* out = (float*)d_out;

  const size_t M4 = (size_t)4 * 1024 * 1024;
  _Float16* q_ws   = (_Float16*)d_ws;
  _Float16* k_ws   = q_ws + M4;
  _Float16* vT_ws  = k_ws + M4;
  _Float16* X16    = vT_ws + M4;
  _Float16* WqkvT  = X16 + M4;
  _Float16* WoT    = WqkvT + (size_t)3 * 1024 * 1024;
  _Float16* aout   = X16;  // X16 dead after qkv phase; reused for attn output

  // Zero the grid-barrier counter (device symbol; capture-safe memset node).
  void* bar_addr = nullptr;
  hipGetSymbolAddress(&bar_addr, HIP_SYMBOL(g_bar));
  hipMemsetAsync(bar_addr, 0, sizeof(int), stream);

  mega<<<512, 256, 0, stream>>>(X, Wq, Wkv, Wo, bo, X16, WqkvT, WoT,
                                q_ws, k_ws, vT_ws, aout, out);
}

// Round 13
// 187.569 us; speedup vs baseline: 2.0740x; 2.0740x over previous
//
#include <hip/hip_runtime.h>
#include <math.h>
#include <stdint.h>

typedef _Float16 half8v __attribute__((ext_vector_type(8)));
typedef _Float16 half4v __attribute__((ext_vector_type(4)));
typedef _Float16 half2v __attribute__((ext_vector_type(2)));
typedef __fp16 fp16x2 __attribute__((ext_vector_type(2)));
typedef float floatx4 __attribute__((ext_vector_type(4)));

#define MFMA16(a, b, c) __builtin_amdgcn_mfma_f32_16x16x32_f16(a, b, c, 0, 0, 0)

// Q pre-scale: 1/sqrt(64) * log2(e), folded so attention uses exp2 directly.
#define QSCALE 0.18033688011112f

// Async global->LDS, 16B per lane. LDS dest must be wave-uniform base + lane*16;
// the GLOBAL source address is per-lane arbitrary (it's a gather).
__device__ __forceinline__ void gld_lds16(const void* g, void* l) {
  __builtin_amdgcn_global_load_lds(
      (const __attribute__((address_space(1))) uint32_t*)(uintptr_t)g,
      (__attribute__((address_space(3))) uint32_t*)(uintptr_t)l, 16, 0, 0);
}

// Packed f32x2 -> f16x2 (rtz), bit-cast to our _Float16 vector type.
__device__ __forceinline__ half2v pk16(float a, float b) {
  fp16x2 t = __builtin_amdgcn_cvt_pkrtz(a, b);
  return __builtin_bit_cast(half2v, t);
}

// LDS bank swizzle for 64-col fp16 tiles (attention), 16B blocks.
__device__ __forceinline__ int swz(int row, int blk) {
  return row * 64 + ((blk ^ (row & 7)) << 3);
}

// LDS bank swizzle for 32-col fp16 GEMM tiles. Unswizzled, row stride = 64 B
// = 16 banks, so b128 frag reads across 16 rows are 8-way conflicted (m136:
// 2.94x). XOR the 16B-chunk index with (row>>1)&3 -> 8 four-bank groups x 2
// lanes = 2-way (free).
__device__ __forceinline__ int gswz(int row, int blk) {
  return row * 32 + ((blk ^ ((row >> 1) & 3)) << 3);
}

// ---------------------------------------------------------------------------
// Prep (fused): blocks 0..2047 convert X fp32->fp16; blocks 2048..3071
// transpose+convert the weights.
// ---------------------------------------------------------------------------
__global__ __launch_bounds__(256) void prep(
    const float* __restrict__ X, const float* __restrict__ Wq,
    const float* __restrict__ Wkv, const float* __restrict__ Wo,
    _Float16* __restrict__ X16, _Float16* __restrict__ WqkvT,
    _Float16* __restrict__ WoT)
{
  __shared__ alignas(16) _Float16 Tt[64 * 68];
  const int bid = blockIdx.x;
  if (bid < 2048) {
    size_t gid = (size_t)bid * 256 + threadIdx.x;
    const float4* src = (const float4*)(X) + gid * 2;
    float4 a = src[0], b = src[1];
    half8v h;
    h[0]=(_Float16)a.x; h[1]=(_Float16)a.y; h[2]=(_Float16)a.z; h[3]=(_Float16)a.w;
    h[4]=(_Float16)b.x; h[5]=(_Float16)b.y; h[6]=(_Float16)b.z; h[7]=(_Float16)b.w;
    *((half8v*)X16 + gid) = h;
    return;
  }
  int b = bid - 2048;
  const float* src; _Float16* dst; int N, tk, tn;
  if (b < 256)      { src = Wq;  dst = WqkvT;                 N = 1024; tk = b & 15;        tn = b >> 4; }
  else if (b < 768) { src = Wkv; dst = WqkvT + (size_t)1024 * 1024; N = 2048; tk = (b - 256) & 15; tn = (b - 256) >> 4; }
  else              { src = Wo;  dst = WoT;                   N = 1024; tk = (b - 768) & 15; tn = (b - 768) >> 4; }

  const int t = threadIdx.x;
  {
    int kg = t >> 4, ng = t & 15;
    const float* sp = src + (size_t)(tk * 64 + kg * 4) * N + tn * 64 + ng * 4;
    float4 r0 = *(const float4*)(sp);
    float4 r1 = *(const float4*)(sp + N);
    float4 r2 = *(const float4*)(sp + 2 * N);
    float4 r3 = *(const float4*)(sp + 3 * N);
    half4v h;
    h[0]=(_Float16)r0.x; h[1]=(_Float16)r1.x; h[2]=(_Float16)r2.x; h[3]=(_Float16)r3.x;
    *(half4v*)&Tt[(ng * 4 + 0) * 68 + kg * 4] = h;
    h[0]=(_Float16)r0.y; h[1]=(_Float16)r1.y; h[2]=(_Float16)r2.y; h[3]=(_Float16)r3.y;
    *(half4v*)&Tt[(ng * 4 + 1) * 68 + kg * 4] = h;
    h[0]=(_Float16)r0.z; h[1]=(_Float16)r1.z; h[2]=(_Float16)r2.z; h[3]=(_Float16)r3.z;
    *(half4v*)&Tt[(ng * 4 + 2) * 68 + kg * 4] = h;
    h[0]=(_Float16)r0.w; h[1]=(_Float16)r1.w; h[2]=(_Float16)r2.w; h[3]=(_Float16)r3.w;
    *(half4v*)&Tt[(ng * 4 + 3) * 68 + kg * 4] = h;
  }
  __syncthreads();
  #pragma unroll
  for (int i = 0; i < 2; i++) {
    int idx = t + i * 256;
    int nl = idx >> 3, k8 = (idx & 7) * 8;
    half8v v = *(half8v*)&Tt[nl * 68 + k8];
    *(half8v*)(dst + (size_t)(tn * 64 + nl) * 1024 + tk * 64 + k8) = v;
  }
}

// ---------------------------------------------------------------------------
// Kernel 1: QKV projection, m97 structure + gswz frag swizzle (8-way -> 2-way
// frag-read conflicts). Staging applies the XOR on the global source chunk.
// ---------------------------------------------------------------------------
__global__ __launch_bounds__(256) void qkv_gemm(
    const _Float16* __restrict__ X16, const _Float16* __restrict__ WqkvT,
    _Float16* __restrict__ q_ws, _Float16* __restrict__ k_ws,
    _Float16* __restrict__ vT_ws)
{
  constexpr int K = 1024;
  __shared__ alignas(16) _Float16 Tt[128 * 136];  // K-loop: As/Bs; epilogue: transpose
  _Float16* As = Tt;
  _Float16* Bs = Tt + 4096;

  const int m0 = blockIdx.x * 128;
  const int n0 = blockIdx.y * 128;

  const int tid  = threadIdx.x;
  const int wave = tid >> 6, lane = tid & 63;
  const int qd = lane >> 4, l15 = lane & 15;
  const int wr = (wave >> 1) * 64, wc = (wave & 1) * 64;
  const int r0i = tid >> 2;
  // Source chunk with the gswz XOR so LDS ends up in swizzled layout.
  const int cbs = (((tid & 3) ^ ((r0i >> 1) & 3))) * 8;

  floatx4 acc[4][4] = {};

  for (int k0 = 0; k0 < K; k0 += 32) {
    gld_lds16(X16 + (size_t)(m0 + r0i) * K + k0 + cbs, &As[tid * 8]);
    gld_lds16(X16 + (size_t)(m0 + 64 + r0i) * K + k0 + cbs, &As[(tid + 256) * 8]);
    gld_lds16(WqkvT + (size_t)(n0 + r0i) * K + k0 + cbs, &Bs[tid * 8]);
    gld_lds16(WqkvT + (size_t)(n0 + 64 + r0i) * K + k0 + cbs, &Bs[(tid + 256) * 8]);
    __syncthreads();
    half8v a[4], b[4];
    #pragma unroll
    for (int it = 0; it < 4; it++)
      a[it] = *(half8v*)&As[gswz(wr + it * 16 + l15, qd)];
    #pragma unroll
    for (int jt = 0; jt < 4; jt++)
      b[jt] = *(half8v*)&Bs[gswz(wc + jt * 16 + l15, qd)];
    #pragma unroll
    for (int it = 0; it < 4; it++)
      #pragma unroll
      for (int jt = 0; jt < 4; jt++)
        acc[it][jt] = MFMA16(a[it], b[jt], acc[it][jt]);
    __syncthreads();
  }

  if (n0 < 2048) {
    #pragma unroll
    for (int it = 0; it < 4; it++) {
      #pragma unroll
      for (int jt = 0; jt < 4; jt++) {
        #pragma unroll
        for (int r = 0; r < 4; r++) {
          int m = m0 + wr + it * 16 + qd * 4 + r;
          int n = n0 + wc + jt * 16 + l15;
          float val = acc[it][jt][r];
          int bb = m >> 11, nn = m & 2047;
          if (n0 < 1024) {
            int h = n >> 6, d = n & 63;
            q_ws[(((size_t)bb * 16 + h) * 2048 + nn) * 64 + d] = (_Float16)(val * QSCALE);
          } else {
            int c = n - 1024, h = c >> 6, d = c & 63;
            k_ws[(((size_t)bb * 16 + h) * 2048 + nn) * 64 + d] = (_Float16)val;
          }
        }
      }
    }
  } else {
    // vT epilogue: transpose in LDS, then coalesced half8 row stores.
    #pragma unroll
    for (int it = 0; it < 4; it++) {
      #pragma unroll
      for (int jt = 0; jt < 4; jt++) {
        #pragma unroll
        for (int r = 0; r < 4; r++) {
          int ml = wr + it * 16 + qd * 4 + r;
          int nl = wc + jt * 16 + l15;
          Tt[nl * 136 + ml] = (_Float16)acc[it][jt][r];
        }
      }
    }
    __syncthreads();
    int row = tid >> 1;
    int mh  = (tid & 1) * 64;
    int c   = (n0 - 2048) + row;
    int bb  = m0 >> 11;
    int nnb = (m0 & 2047) + mh;
    _Float16* dstp =
        vT_ws + (((size_t)bb * 16 + (c >> 6)) * 64 + (c & 63)) * 2048 + nnb;
    #pragma unroll
    for (int i = 0; i < 8; i++)
      *(half8v*)(dstp + i * 8) = *(half8v*)&Tt[row * 136 + mh + i * 8];
  }
}

// ---------------------------------------------------------------------------
// Kernel 2: flash attention v7 (unchanged from R10 — the 190.3 us control).
// ---------------------------------------------------------------------------
__global__ __launch_bounds__(128, 2) void attn_kernel(
    const _Float16* __restrict__ q_ws, const _Float16* __restrict__ k_ws,
    const _Float16* __restrict__ vT_ws, _Float16* __restrict__ aout)
{
  constexpr int N = 2048;
  __shared__ alignas(16) _Float16 Qs[64 * 64];      // Q staging -> P buffer
  __shared__ alignas(16) _Float16 Ks[2][64 * 64];   // double-buffered K
  __shared__ alignas(16) _Float16 Vts[2][64 * 64];  // double-buffered V^T

  const int id = blockIdx.x;
  const int bh = ((id >> 8) << 3) | (id & 7);
  const int qt = (id >> 3) & 31;

  const _Float16* Qp = q_ws + (size_t)bh * N * 64;
  const _Float16* Kp = k_ws + (size_t)bh * N * 64;
  const _Float16* Vp = vT_ws + (size_t)bh * 64 * N;

  const int tid = threadIdx.x, wave = tid >> 6, lane = tid & 63;
  const int qd = lane >> 4, l15 = lane & 15;
  const int q0 = qt * 64;
  const int wbase = wave * 32;

  // Prologue: async-stage Q tile and K/V tile 0 (source-side XOR swizzle).
  #pragma unroll
  for (int i = 0; i < 4; i++) {
    int idx = tid + i * 128;
    int r = idx >> 3, cb = (idx ^ r) & 7;
    gld_lds16(Qp + (size_t)(q0 + r) * 64 + cb * 8, &Qs[idx * 8]);
    gld_lds16(Kp + (size_t)r * 64 + cb * 8, &Ks[0][idx * 8]);
    gld_lds16(Vp + (size_t)r * N + cb * 8, &Vts[0][idx * 8]);
  }
  __syncthreads();  // drains vmcnt: Q, K0, V0 resident

  half8v qf[2][2];
  #pragma unroll
  for (int m = 0; m < 2; m++)
    #pragma unroll
    for (int ks = 0; ks < 2; ks++)
      qf[m][ks] = *(half8v*)&Qs[swz(wbase + m * 16 + l15, ks * 4 + qd)];

  floatx4 o[2][4] = {};
  float lsum[2] = {};

  int p = 0;
  for (int kv0 = 0; kv0 < N; kv0 += 64) {
    const bool more = (kv0 + 64) < N;
    if (more) {
      int kvn = kv0 + 64;
      #pragma unroll
      for (int i = 0; i < 4; i++) {
        int idx = tid + i * 128;
        int r = idx >> 3, cb = (idx ^ r) & 7;
        gld_lds16(Kp + (size_t)(kvn + r) * 64 + cb * 8, &Ks[p ^ 1][idx * 8]);
        gld_lds16(Vp + (size_t)r * N + kvn + cb * 8, &Vts[p ^ 1][idx * 8]);
      }
    }

    // S^T = K·Q^T : s[nt][m] C-layout kv = nt*16+qd*4+r, q = m*16+l15.
    floatx4 s[4][2] = {};
    #pragma unroll
    for (int ks = 0; ks < 2; ks++) {
      half8v kf[4];
      #pragma unroll
      for (int nt = 0; nt < 4; nt++)
        kf[nt] = *(half8v*)&Ks[p][swz(nt * 16 + l15, ks * 4 + qd)];
      #pragma unroll
      for (int nt = 0; nt < 4; nt++)
        #pragma unroll
        for (int m = 0; m < 2; m++)
          s[nt][m] = MFMA16(kf[nt], qf[m][ks], s[nt][m]);
    }

    // p = 2^s; per-lane partial row sums (q = l15); pack half4 and write to
    // P buffer (wave-private rows of Qs) as kv-contiguous b64.
    #pragma unroll
    for (int m = 0; m < 2; m++) {
      #pragma unroll
      for (int nt = 0; nt < 4; nt++) {
        float p0 = __builtin_amdgcn_exp2f(s[nt][m][0]);
        float p1 = __builtin_amdgcn_exp2f(s[nt][m][1]);
        float p2 = __builtin_amdgcn_exp2f(s[nt][m][2]);
        float p3 = __builtin_amdgcn_exp2f(s[nt][m][3]);
        lsum[m] += (p0 + p1) + (p2 + p3);
        half2v h01 = pk16(p0, p1);
        half2v h23 = pk16(p2, p3);
        half4v pk;
        pk[0] = h01[0]; pk[1] = h01[1]; pk[2] = h23[0]; pk[3] = h23[1];
        *(half4v*)&Qs[swz(wbase + m * 16 + l15, 2 * nt + (qd >> 1)) +
                      (qd & 1) * 4] = pk;
      }
    }

    // O += P·V, full-rate K=32 MFMA.
    #pragma unroll
    for (int ks = 0; ks < 2; ks++) {
      half8v pf[2], vf[4];
      #pragma unroll
      for (int m = 0; m < 2; m++)
        pf[m] = *(half8v*)&Qs[swz(wbase + m * 16 + l15, 4 * ks + qd)];
      #pragma unroll
      for (int nt = 0; nt < 4; nt++)
        vf[nt] = *(half8v*)&Vts[p][swz(nt * 16 + l15, 4 * ks + qd)];
      #pragma unroll
      for (int m = 0; m < 2; m++)
        #pragma unroll
        for (int nt = 0; nt < 4; nt++)
          o[m][nt] = MFMA16(pf[m], vf[nt], o[m][nt]);
    }

    if (more) __syncthreads();
    p ^= 1;
  }

  #pragma unroll
  for (int m = 0; m < 2; m++) {
    lsum[m] += __shfl_xor(lsum[m], 16);
    lsum[m] += __shfl_xor(lsum[m], 32);
  }

  const int bb = bh >> 4, hh = bh & 15;
  #pragma unroll
  for (int m = 0; m < 2; m++) {
    #pragma unroll
    for (int r = 0; r < 4; r++) {
      float inv = 1.0f / __shfl(lsum[m], qd * 4 + r);
      int n = q0 + wbase + m * 16 + qd * 4 + r;
      #pragma unroll
      for (int dt = 0; dt < 4; dt++) {
        int d = dt * 16 + l15;
        aout[((size_t)(bb * 2048 + n)) * 1024 + hh * 64 + d] =
            (_Float16)(o[m][dt][r] * inv);
      }
    }
  }
}

// ---------------------------------------------------------------------------
// Kernel 3: out projection, 64x128 tiles (2 blocks/CU) + gswz frag swizzle.
// ---------------------------------------------------------------------------
__global__ __launch_bounds__(256) void out_gemm(
    const _Float16* __restrict__ A, const _Float16* __restrict__ WoT,
    const float* __restrict__ bo, float* __restrict__ Out)
{
  constexpr int K = 1024;
  __shared__ alignas(16) _Float16 As[64 * 32];
  __shared__ alignas(16) _Float16 Bs[128 * 32];

  const int m0 = blockIdx.x * 64;
  const int n0 = blockIdx.y * 128;
  const int tid = threadIdx.x;
  const int wave = tid >> 6, lane = tid & 63;
  const int qd = lane >> 4, l15 = lane & 15;
  const int wr = (wave >> 1) * 32, wc = (wave & 1) * 64;
  const int r0i = tid >> 2;
  const int cbs = (((tid & 3) ^ ((r0i >> 1) & 3))) * 8;

  floatx4 acc[2][4] = {};

  for (int k0 = 0; k0 < K; k0 += 32) {
    gld_lds16(A + (size_t)(m0 + r0i) * K + k0 + cbs, &As[tid * 8]);
    gld_lds16(WoT + (size_t)(n0 + r0i) * K + k0 + cbs, &Bs[tid * 8]);
    gld_lds16(WoT + (size_t)(n0 + 64 + r0i) * K + k0 + cbs, &Bs[(tid + 256) * 8]);
    __syncthreads();
    half8v a[2], b[4];
    #pragma unroll
    for (int it = 0; it < 2; it++)
      a[it] = *(half8v*)&As[gswz(wr + it * 16 + l15, qd)];
    #pragma unroll
    for (int jt = 0; jt < 4; jt++)
      b[jt] = *(half8v*)&Bs[gswz(wc + jt * 16 + l15, qd)];
    #pragma unroll
    for (int it = 0; it < 2; it++)
      #pragma unroll
      for (int jt = 0; jt < 4; jt++)
        acc[it][jt] = MFMA16(a[it], b[jt], acc[it][jt]);
    __syncthreads();
  }

  #pragma unroll
  for (int it = 0; it < 2; it++) {
    #pragma unroll
    for (int jt = 0; jt < 4; jt++) {
      int n = n0 + wc + jt * 16 + l15;
      float bias = bo[n];
      #pragma unroll
      for (int r = 0; r < 4; r++) {
        int m = m0 + wr + it * 16 + qd * 4 + r;
        Out[(size_t)m * 1024 + n] = acc[it][jt][r] + bias;
      }
    }
  }
}

// ---------------------------------------------------------------------------
extern "C" void kernel_launch(void* const* d_in, const int* in_sizes, int n_in,
                              void* d_out, int out_size, void* d_ws, size_t ws_size,
                              hipStream_t stream) {
  const float* X   = (const float*)d_in[0];
  const float* Wq  = (const float*)d_in[1];
  const float* Wkv = (const float*)d_in[2];
  const float* Wo  = (const float*)d_in[3];
  const float* bo  = (const float*)d_in[4];
  float* out = (float*)d_out;

  const size_t M4 = (size_t)4 * 1024 * 1024;
  _Float16* q_ws   = (_Float16*)d_ws;
  _Float16* k_ws   = q_ws + M4;
  _Float16* vT_ws  = k_ws + M4;
  _Float16* X16    = vT_ws + M4;
  _Float16* WqkvT  = X16 + M4;
  _Float16* WoT    = WqkvT + (size_t)3 * 1024 * 1024;
  _Float16* aout   = X16;  // X16 dead after qkv_gemm

  prep<<<3072, 256, 0, stream>>>(X, Wq, Wkv, Wo, X16, WqkvT, WoT);
  qkv_gemm<<<dim3(32, 24), 256, 0, stream>>>(X16, WqkvT, q_ws, k_ws, vT_ws);
  attn_kernel<<<1024, 128, 0, stream>>>(q_ws, k_ws, vT_ws, aout);
  out_gemm<<<dim3(64, 8), 256, 0, stream>>>(aout, WoT, bo, out);
}

// Round 14
// 187.294 us; speedup vs baseline: 2.0771x; 1.0015x over previous
//
#include <hip/hip_runtime.h>
#include <math.h>
#include <stdint.h>

typedef _Float16 half8v __attribute__((ext_vector_type(8)));
typedef _Float16 half4v __attribute__((ext_vector_type(4)));
typedef _Float16 half2v __attribute__((ext_vector_type(2)));
typedef __fp16 fp16x2 __attribute__((ext_vector_type(2)));
typedef float floatx4 __attribute__((ext_vector_type(4)));

#define MFMA16(a, b, c) __builtin_amdgcn_mfma_f32_16x16x32_f16(a, b, c, 0, 0, 0)

// Q pre-scale: 1/sqrt(64) * log2(e), folded so attention uses exp2 directly.
#define QSCALE 0.18033688011112f

// Async global->LDS, 16B per lane. LDS dest must be wave-uniform base + lane*16;
// the GLOBAL source address is per-lane arbitrary (it's a gather).
__device__ __forceinline__ void gld_lds16(const void* g, void* l) {
  __builtin_amdgcn_global_load_lds(
      (const __attribute__((address_space(1))) uint32_t*)(uintptr_t)g,
      (__attribute__((address_space(3))) uint32_t*)(uintptr_t)l, 16, 0, 0);
}

// Packed f32x2 -> f16x2 (rtz), bit-cast to our _Float16 vector type.
__device__ __forceinline__ half2v pk16(float a, float b) {
  fp16x2 t = __builtin_amdgcn_cvt_pkrtz(a, b);
  return __builtin_bit_cast(half2v, t);
}

// LDS bank swizzle for 64-col fp16 tiles (128B rows), 16B blocks.
__device__ __forceinline__ int swz(int row, int blk) {
  return row * 64 + ((blk ^ (row & 7)) << 3);
}

// LDS bank swizzle for 32-col fp16 tiles (64B rows = 16 banks): XOR chunk
// with (row>>1)&3 so 16-row b128 frag reads are 2-way, not 8-way.
__device__ __forceinline__ int vswz(int row, int blk) {
  return row * 32 + ((blk ^ ((row >> 1) & 3)) << 3);
}

// GEMM 32-col tile swizzle (same math as vswz; kept separate for clarity).
__device__ __forceinline__ int gswz(int row, int blk) {
  return row * 32 + ((blk ^ ((row >> 1) & 3)) << 3);
}

// ---------------------------------------------------------------------------
// Prep (fused): blocks 0..2047 convert X fp32->fp16; blocks 2048..3071
// transpose+convert the weights.  (unchanged from R13)
// ---------------------------------------------------------------------------
__global__ __launch_bounds__(256) void prep(
    const float* __restrict__ X, const float* __restrict__ Wq,
    const float* __restrict__ Wkv, const float* __restrict__ Wo,
    _Float16* __restrict__ X16, _Float16* __restrict__ WqkvT,
    _Float16* __restrict__ WoT)
{
  __shared__ alignas(16) _Float16 Tt[64 * 68];
  const int bid = blockIdx.x;
  if (bid < 2048) {
    size_t gid = (size_t)bid * 256 + threadIdx.x;
    const float4* src = (const float4*)(X) + gid * 2;
    float4 a = src[0], b = src[1];
    half8v h;
    h[0]=(_Float16)a.x; h[1]=(_Float16)a.y; h[2]=(_Float16)a.z; h[3]=(_Float16)a.w;
    h[4]=(_Float16)b.x; h[5]=(_Float16)b.y; h[6]=(_Float16)b.z; h[7]=(_Float16)b.w;
    *((half8v*)X16 + gid) = h;
    return;
  }
  int b = bid - 2048;
  const float* src; _Float16* dst; int N, tk, tn;
  if (b < 256)      { src = Wq;  dst = WqkvT;                 N = 1024; tk = b & 15;        tn = b >> 4; }
  else if (b < 768) { src = Wkv; dst = WqkvT + (size_t)1024 * 1024; N = 2048; tk = (b - 256) & 15; tn = (b - 256) >> 4; }
  else              { src = Wo;  dst = WoT;                   N = 1024; tk = (b - 768) & 15; tn = (b - 768) >> 4; }

  const int t = threadIdx.x;
  {
    int kg = t >> 4, ng = t & 15;
    const float* sp = src + (size_t)(tk * 64 + kg * 4) * N + tn * 64 + ng * 4;
    float4 r0 = *(const float4*)(sp);
    float4 r1 = *(const float4*)(sp + N);
    float4 r2 = *(const float4*)(sp + 2 * N);
    float4 r3 = *(const float4*)(sp + 3 * N);
    half4v h;
    h[0]=(_Float16)r0.x; h[1]=(_Float16)r1.x; h[2]=(_Float16)r2.x; h[3]=(_Float16)r3.x;
    *(half4v*)&Tt[(ng * 4 + 0) * 68 + kg * 4] = h;
    h[0]=(_Float16)r0.y; h[1]=(_Float16)r1.y; h[2]=(_Float16)r2.y; h[3]=(_Float16)r3.y;
    *(half4v*)&Tt[(ng * 4 + 1) * 68 + kg * 4] = h;
    h[0]=(_Float16)r0.z; h[1]=(_Float16)r1.z; h[2]=(_Float16)r2.z; h[3]=(_Float16)r3.z;
    *(half4v*)&Tt[(ng * 4 + 2) * 68 + kg * 4] = h;
    h[0]=(_Float16)r0.w; h[1]=(_Float16)r1.w; h[2]=(_Float16)r2.w; h[3]=(_Float16)r3.w;
    *(half4v*)&Tt[(ng * 4 + 3) * 68 + kg * 4] = h;
  }
  __syncthreads();
  #pragma unroll
  for (int i = 0; i < 2; i++) {
    int idx = t + i * 256;
    int nl = idx >> 3, k8 = (idx & 7) * 8;
    half8v v = *(half8v*)&Tt[nl * 68 + k8];
    *(half8v*)(dst + (size_t)(tn * 64 + nl) * 1024 + tk * 64 + k8) = v;
  }
}

// ---------------------------------------------------------------------------
// Kernel 1: QKV projection (unchanged from R13: m97 structure + gswz).
// ---------------------------------------------------------------------------
__global__ __launch_bounds__(256) void qkv_gemm(
    const _Float16* __restrict__ X16, const _Float16* __restrict__ WqkvT,
    _Float16* __restrict__ q_ws, _Float16* __restrict__ k_ws,
    _Float16* __restrict__ vT_ws)
{
  constexpr int K = 1024;
  __shared__ alignas(16) _Float16 Tt[128 * 136];
  _Float16* As = Tt;
  _Float16* Bs = Tt + 4096;

  const int m0 = blockIdx.x * 128;
  const int n0 = blockIdx.y * 128;

  const int tid  = threadIdx.x;
  const int wave = tid >> 6, lane = tid & 63;
  const int qd = lane >> 4, l15 = lane & 15;
  const int wr = (wave >> 1) * 64, wc = (wave & 1) * 64;
  const int r0i = tid >> 2;
  const int cbs = (((tid & 3) ^ ((r0i >> 1) & 3))) * 8;

  floatx4 acc[4][4] = {};

  for (int k0 = 0; k0 < K; k0 += 32) {
    gld_lds16(X16 + (size_t)(m0 + r0i) * K + k0 + cbs, &As[tid * 8]);
    gld_lds16(X16 + (size_t)(m0 + 64 + r0i) * K + k0 + cbs, &As[(tid + 256) * 8]);
    gld_lds16(WqkvT + (size_t)(n0 + r0i) * K + k0 + cbs, &Bs[tid * 8]);
    gld_lds16(WqkvT + (size_t)(n0 + 64 + r0i) * K + k0 + cbs, &Bs[(tid + 256) * 8]);
    __syncthreads();
    half8v a[4], b[4];
    #pragma unroll
    for (int it = 0; it < 4; it++)
      a[it] = *(half8v*)&As[gswz(wr + it * 16 + l15, qd)];
    #pragma unroll
    for (int jt = 0; jt < 4; jt++)
      b[jt] = *(half8v*)&Bs[gswz(wc + jt * 16 + l15, qd)];
    #pragma unroll
    for (int it = 0; it < 4; it++)
      #pragma unroll
      for (int jt = 0; jt < 4; jt++)
        acc[it][jt] = MFMA16(a[it], b[jt], acc[it][jt]);
    __syncthreads();
  }

  if (n0 < 2048) {
    #pragma unroll
    for (int it = 0; it < 4; it++) {
      #pragma unroll
      for (int jt = 0; jt < 4; jt++) {
        #pragma unroll
        for (int r = 0; r < 4; r++) {
          int m = m0 + wr + it * 16 + qd * 4 + r;
          int n = n0 + wc + jt * 16 + l15;
          float val = acc[it][jt][r];
          int bb = m >> 11, nn = m & 2047;
          if (n0 < 1024) {
            int h = n >> 6, d = n & 63;
            q_ws[(((size_t)bb * 16 + h) * 2048 + nn) * 64 + d] = (_Float16)(val * QSCALE);
          } else {
            int c = n - 1024, h = c >> 6, d = c & 63;
            k_ws[(((size_t)bb * 16 + h) * 2048 + nn) * 64 + d] = (_Float16)val;
          }
        }
      }
    }
  } else {
    #pragma unroll
    for (int it = 0; it < 4; it++) {
      #pragma unroll
      for (int jt = 0; jt < 4; jt++) {
        #pragma unroll
        for (int r = 0; r < 4; r++) {
          int ml = wr + it * 16 + qd * 4 + r;
          int nl = wc + jt * 16 + l15;
          Tt[nl * 136 + ml] = (_Float16)acc[it][jt][r];
        }
      }
    }
    __syncthreads();
    int row = tid >> 1;
    int mh  = (tid & 1) * 64;
    int c   = (n0 - 2048) + row;
    int bb  = m0 >> 11;
    int nnb = (m0 & 2047) + mh;
    _Float16* dstp =
        vT_ws + (((size_t)bb * 16 + (c >> 6)) * 64 + (c & 63)) * 2048 + nnb;
    #pragma unroll
    for (int i = 0; i < 8; i++)
      *(half8v*)(dstp + i * 8) = *(half8v*)&Tt[row * 136 + mh + i * 8];
  }
}

// ---------------------------------------------------------------------------
// Kernel 2: flash attention v8 — 24 KB LDS for 4 blocks/CU (8 waves/CU).
// KV tile halved to 32 rows, still double-buffered; 64 iters, 1 barrier/iter.
// Per-wave total LDS work unchanged; overlap +33%. K tile keeps swz (128B
// rows); V^T tile rows are now 64B -> vswz. PV is a single K=32 MFMA step.
// ---------------------------------------------------------------------------
__global__ __launch_bounds__(128, 2) void attn_kernel(
    const _Float16* __restrict__ q_ws, const _Float16* __restrict__ k_ws,
    const _Float16* __restrict__ vT_ws, _Float16* __restrict__ aout)
{
  constexpr int N = 2048;
  __shared__ alignas(16) _Float16 Qs[64 * 64];      // 8 KB  Q -> P buffer
  __shared__ alignas(16) _Float16 Ks[2][32 * 64];   // 8 KB  dbuf K  [kv][d]
  __shared__ alignas(16) _Float16 Vts[2][64 * 32];  // 8 KB  dbuf V^T [d][kv]

  const int id = blockIdx.x;
  const int bh = ((id >> 8) << 3) | (id & 7);
  const int qt = (id >> 3) & 31;

  const _Float16* Qp = q_ws + (size_t)bh * N * 64;
  const _Float16* Kp = k_ws + (size_t)bh * N * 64;
  const _Float16* Vp = vT_ws + (size_t)bh * 64 * N;

  const int tid = threadIdx.x, wave = tid >> 6, lane = tid & 63;
  const int qd = lane >> 4, l15 = lane & 15;
  const int q0 = qt * 64;
  const int wbase = wave * 32;

  // Prologue: stage Q (64x64) + K0 (32x64, swz) + V0 (64x32, vswz).
  #pragma unroll
  for (int i = 0; i < 4; i++) {
    int idx = tid + i * 128;
    int r = idx >> 3, cb = (idx ^ r) & 7;
    gld_lds16(Qp + (size_t)(q0 + r) * 64 + cb * 8, &Qs[idx * 8]);
  }
  #pragma unroll
  for (int i = 0; i < 2; i++) {
    int idx = tid + i * 128;
    { int r = idx >> 3, cb = (idx ^ r) & 7;
      gld_lds16(Kp + (size_t)r * 64 + cb * 8, &Ks[0][idx * 8]); }
    { int r = idx >> 2, cb = ((idx & 3) ^ ((r >> 1) & 3));
      gld_lds16(Vp + (size_t)r * N + cb * 8, &Vts[0][idx * 8]); }
  }
  __syncthreads();  // drains vmcnt: Q, K0, V0 resident

  half8v qf[2][2];
  #pragma unroll
  for (int m = 0; m < 2; m++)
    #pragma unroll
    for (int ks = 0; ks < 2; ks++)
      qf[m][ks] = *(half8v*)&Qs[swz(wbase + m * 16 + l15, ks * 4 + qd)];

  floatx4 o[2][4] = {};
  float lsum[2] = {};

  int p = 0;
  for (int kv0 = 0; kv0 < N; kv0 += 32) {
    const bool more = (kv0 + 32) < N;
    // Async prefetch next 32-row K/V tile into buf[p^1].
    if (more) {
      int kvn = kv0 + 32;
      #pragma unroll
      for (int i = 0; i < 2; i++) {
        int idx = tid + i * 128;
        { int r = idx >> 3, cb = (idx ^ r) & 7;
          gld_lds16(Kp + (size_t)(kvn + r) * 64 + cb * 8,
                    &Ks[p ^ 1][idx * 8]); }
        { int r = idx >> 2, cb = ((idx & 3) ^ ((r >> 1) & 3));
          gld_lds16(Vp + (size_t)r * N + kvn + cb * 8,
                    &Vts[p ^ 1][idx * 8]); }
      }
    }

    // S^T = K·Q^T : s[nt][m] C-layout kv = nt*16+qd*4+r, q = m*16+l15.
    floatx4 s[2][2] = {};
    #pragma unroll
    for (int ks = 0; ks < 2; ks++) {
      half8v kf[2];
      #pragma unroll
      for (int nt = 0; nt < 2; nt++)
        kf[nt] = *(half8v*)&Ks[p][swz(nt * 16 + l15, ks * 4 + qd)];
      #pragma unroll
      for (int nt = 0; nt < 2; nt++)
        #pragma unroll
        for (int m = 0; m < 2; m++)
          s[nt][m] = MFMA16(kf[nt], qf[m][ks], s[nt][m]);
    }

    // p = 2^s; per-lane partial row sums (q=l15); pack -> P rows of Qs.
    // Chunk c = 2nt+(qd>>1) in [0,3] holds kv c*8..c*8+7 (matches pf read).
    #pragma unroll
    for (int m = 0; m < 2; m++) {
      #pragma unroll
      for (int nt = 0; nt < 2; nt++) {
        float p0 = __builtin_amdgcn_exp2f(s[nt][m][0]);
        float p1 = __builtin_amdgcn_exp2f(s[nt][m][1]);
        float p2 = __builtin_amdgcn_exp2f(s[nt][m][2]);
        float p3 = __builtin_amdgcn_exp2f(s[nt][m][3]);
        lsum[m] += (p0 + p1) + (p2 + p3);
        half2v h01 = pk16(p0, p1);
        half2v h23 = pk16(p2, p3);
        half4v pk;
        pk[0] = h01[0]; pk[1] = h01[1]; pk[2] = h23[0]; pk[3] = h23[1];
        *(half4v*)&Qs[swz(wbase + m * 16 + l15, 2 * nt + (qd >> 1)) +
                      (qd & 1) * 4] = pk;
      }
    }

    // O += P·V: single K=32 MFMA step over the 32-kv tile.
    // pf: A[q=l15][kv=qd*8+j] = chunk qd of P row. vf: B[kv=qd*8+j][d] from
    // Vts[d=dt*16+l15][chunk qd] (vswz).
    {
      half8v pf[2], vf[4];
      #pragma unroll
      for (int m = 0; m < 2; m++)
        pf[m] = *(half8v*)&Qs[swz(wbase + m * 16 + l15, qd)];
      #pragma unroll
      for (int dt = 0; dt < 4; dt++)
        vf[dt] = *(half8v*)&Vts[p][vswz(dt * 16 + l15, qd)];
      #pragma unroll
      for (int m = 0; m < 2; m++)
        #pragma unroll
        for (int dt = 0; dt < 4; dt++)
          o[m][dt] = MFMA16(pf[m], vf[dt], o[m][dt]);
    }

    if (more) __syncthreads();
    p ^= 1;
  }

  #pragma unroll
  for (int m = 0; m < 2; m++) {
    lsum[m] += __shfl_xor(lsum[m], 16);
    lsum[m] += __shfl_xor(lsum[m], 32);
  }

  const int bb = bh >> 4, hh = bh & 15;
  #pragma unroll
  for (int m = 0; m < 2; m++) {
    #pragma unroll
    for (int r = 0; r < 4; r++) {
      float inv = 1.0f / __shfl(lsum[m], qd * 4 + r);
      int n = q0 + wbase + m * 16 + qd * 4 + r;
      #pragma unroll
      for (int dt = 0; dt < 4; dt++) {
        int d = dt * 16 + l15;
        aout[((size_t)(bb * 2048 + n)) * 1024 + hh * 64 + d] =
            (_Float16)(o[m][dt][r] * inv);
      }
    }
  }
}

// ---------------------------------------------------------------------------
// Kernel 3: out projection (unchanged from R13).
// ---------------------------------------------------------------------------
__global__ __launch_bounds__(256) void out_gemm(
    const _Float16* __restrict__ A, const _Float16* __restrict__ WoT,
    const float* __restrict__ bo, float* __restrict__ Out)
{
  constexpr int K = 1024;
  __shared__ alignas(16) _Float16 As[64 * 32];
  __shared__ alignas(16) _Float16 Bs[128 * 32];

  const int m0 = blockIdx.x * 64;
  const int n0 = blockIdx.y * 128;
  const int tid = threadIdx.x;
  const int wave = tid >> 6, lane = tid & 63;
  const int qd = lane >> 4, l15 = lane & 15;
  const int wr = (wave >> 1) * 32, wc = (wave & 1) * 64;
  const int r0i = tid >> 2;
  const int cbs = (((tid & 3) ^ ((r0i >> 1) & 3))) * 8;

  floatx4 acc[2][4] = {};

  for (int k0 = 0; k0 < K; k0 += 32) {
    gld_lds16(A + (size_t)(m0 + r0i) * K + k0 + cbs, &As[tid * 8]);
    gld_lds16(WoT + (size_t)(n0 + r0i) * K + k0 + cbs, &Bs[tid * 8]);
    gld_lds16(WoT + (size_t)(n0 + 64 + r0i) * K + k0 + cbs, &Bs[(tid + 256) * 8]);
    __syncthreads();
    half8v a[2], b[4];
    #pragma unroll
    for (int it = 0; it < 2; it++)
      a[it] = *(half8v*)&As[gswz(wr + it * 16 + l15, qd)];
    #pragma unroll
    for (int jt = 0; jt < 4; jt++)
      b[jt] = *(half8v*)&Bs[gswz(wc + jt * 16 + l15, qd)];
    #pragma unroll
    for (int it = 0; it < 2; it++)
      #pragma unroll
      for (int jt = 0; jt < 4; jt++)
        acc[it][jt] = MFMA16(a[it], b[jt], acc[it][jt]);
    __syncthreads();
  }

  #pragma unroll
  for (int it = 0; it < 2; it++) {
    #pragma unroll
    for (int jt = 0; jt < 4; jt++) {
      int n = n0 + wc + jt * 16 + l15;
      float bias = bo[n];
      #pragma unroll
      for (int r = 0; r < 4; r++) {
        int m = m0 + wr + it * 16 + qd * 4 + r;
        Out[(size_t)m * 1024 + n] = acc[it][jt][r] + bias;
      }
    }
  }
}

// ---------------------------------------------------------------------------
extern "C" void kernel_launch(void* const* d_in, const int* in_sizes, int n_in,
                              void* d_out, int out_size, void* d_ws, size_t ws_size,
                              hipStream_t stream) {
  const float* X   = (const float*)d_in[0];
  const float* Wq  = (const float*)d_in[1];
  const float* Wkv = (const float*)d_in[2];
  const float* Wo  = (const float*)d_in[3];
  const float* bo  = (const float*)d_in[4];
  float* out = (float*)d_out;

  const size_t M4 = (size_t)4 * 1024 * 1024;
  _Float16* q_ws   = (_Float16*)d_ws;
  _Float16* k_ws   = q_ws + M4;
  _Float16* vT_ws  = k_ws + M4;
  _Float16* X16    = vT_ws + M4;
  _Float16* WqkvT  = X16 + M4;
  _Float16* WoT    = WqkvT + (size_t)3 * 1024 * 1024;
  _Float16* aout   = X16;  // X16 dead after qkv_gemm

  prep<<<3072, 256, 0, stream>>>(X, Wq, Wkv, Wo, X16, WqkvT, WoT);
  qkv_gemm<<<dim3(32, 24), 256, 0, stream>>>(X16, WqkvT, q_ws, k_ws, vT_ws);
  attn_kernel<<<1024, 128, 0, stream>>>(q_ws, k_ws, vT_ws, aout);
  out_gemm<<<dim3(64, 8), 256, 0, stream>>>(aout, WoT, bo, out);
}